// Round 18
// baseline (2123.519 us; speedup 1.0000x reference)
//
#include <hip/hip_runtime.h>
#include <hip/hip_fp16.h>

#define TS 40
#define NB 2048
#define NU 1024
#define NI 1024
#define ND 2048
#define UD (1024 * 2048)  // elems in one W_t (4 MB as f16)

typedef _Float16 half8 __attribute__((ext_vector_type(8)));
typedef _Float16 half4v __attribute__((ext_vector_type(4)));
typedef float floatx4 __attribute__((ext_vector_type(4)));

__device__ __forceinline__ float tanh_fast(float v) {
  float e = __expf(2.0f * v);
  return 1.0f - 2.0f / (e + 1.0f);  // inf-safe
}

__device__ __forceinline__ void gload16(const void* g, void* l) {
  __builtin_amdgcn_global_load_lds(
      (const __attribute__((address_space(1))) void*)g,
      (__attribute__((address_space(3))) void*)l, 16, 0, 0);
}

// ===== fragment-major tile layout (verified R6-R16) =========================
__device__ __forceinline__ int tile_off(int r, int c8) {
  return (((((r >> 4) * 2 + (c8 >> 2)) << 6) + ((c8 & 3) << 4) + (r & 15)) << 4);
}

// W_tiled:  [t][ut 0..15][kt 0..31][8192B]  (kt<16: h-part, kt>=16: x-part)
// X_tiled:  [t][bt 0..31][kt 0..15][8192B]
// h_tiled:  [slot][bt 0..31][ut 0..15][8192B]
// pre_frag: [t][bid_s = bt+32*ut][tid_s 0..511][8 f16]
// done:     [t][bt] int counters (flag sync for serial7)

// ---------------- merged prep (verified R14/R16) + FIXED flag zeroing -------
__global__ __launch_bounds__(256) void prep_all(
    const float* __restrict__ Qw, const float* __restrict__ Bt,
    _Float16* __restrict__ W,
    const float* __restrict__ x, _Float16* __restrict__ X,
    const float* __restrict__ h0, _Float16* __restrict__ hb,
    int* __restrict__ done)
{
  __shared__ char shm[66816];
  const int tid = threadIdx.x;
  const int bid = blockIdx.x;

  if (bid < 512) {
    // ---- wprep ----
    _Float16* ldsQ = (_Float16*)shm;
    float* ldsB = (float*)(shm + 65536);
    const int kt = bid & 31;
    const int ut = bid >> 5;
    for (int i = tid; i < TS * 8; i += 256) ldsB[i] = Bt[i];
    const float* qb = Qw + (size_t)(kt * 64) * 8192 + ut * 512;
#pragma unroll
    for (int i = 0; i < 32; ++i) {
      int s = i * 256 + tid;
      int dk = s >> 7, c4 = s & 127;
      float4 v = *(const float4*)(qb + (size_t)dk * 8192 + c4 * 4);
      _Float16* d = &ldsQ[dk * 512 + c4 * 4];
      d[0] = (_Float16)v.x; d[1] = (_Float16)v.y;
      d[2] = (_Float16)v.z; d[3] = (_Float16)v.w;
    }
    __syncthreads();
    const int w = tid >> 6, lane = tid & 63;
    const int dur = lane & 7, ko = lane >> 3;
#pragma unroll 1
    for (int sp = 0; sp < 2; ++sp) {
      const int stripe = w * 2 + sp;
      const int du = stripe * 8 + dur;
      float Q[8][8];
#pragma unroll
      for (int j = 0; j < 8; ++j)
#pragma unroll
        for (int q = 0; q < 8; ++q)
          Q[j][q] = (float)ldsQ[(ko * 8 + j) * 512 + du * 8 + q];
      const int obase = tile_off(du, ko);
#pragma unroll 1
      for (int t = 0; t < TS; ++t) {
        float b[8];
#pragma unroll
        for (int q = 0; q < 8; ++q) b[q] = ldsB[t * 8 + q];
        half8 v;
#pragma unroll
        for (int j = 0; j < 8; ++j) {
          float s = 0.f;
#pragma unroll
          for (int q = 0; q < 8; ++q) s += Q[j][q] * b[q];
          v[j] = (_Float16)s;
        }
        size_t tile = ((size_t)t * 16 + ut) * 32 + kt;
        *(half8*)((char*)W + tile * 8192 + obase) = v;
      }
    }
  } else if (bid < 1792) {
    // ---- xprep ----
    char* stage = shm;
    const int b2 = bid - 512;
    const int bt = b2 & 31, t = b2 >> 5;
    char* outb = (char*)X + ((size_t)(t * 32 + bt) * 16) * 8192;
    const int r = tid >> 2, cq = tid & 3;
#pragma unroll 1
    for (int kt = 0; kt < 16; ++kt) {
      const float* src =
          x + (size_t)(bt * 64 + r) * (TS * NI) + (size_t)t * NI + kt * 64 + cq * 16;
      float4 a0 = *(const float4*)(src);
      float4 a1 = *(const float4*)(src + 4);
      float4 a2 = *(const float4*)(src + 8);
      float4 a3 = *(const float4*)(src + 12);
      half8 h0v, h1v;
      h0v[0] = (_Float16)a0.x; h0v[1] = (_Float16)a0.y;
      h0v[2] = (_Float16)a0.z; h0v[3] = (_Float16)a0.w;
      h0v[4] = (_Float16)a1.x; h0v[5] = (_Float16)a1.y;
      h0v[6] = (_Float16)a1.z; h0v[7] = (_Float16)a1.w;
      h1v[0] = (_Float16)a2.x; h1v[1] = (_Float16)a2.y;
      h1v[2] = (_Float16)a2.z; h1v[3] = (_Float16)a2.w;
      h1v[4] = (_Float16)a3.x; h1v[5] = (_Float16)a3.y;
      h1v[6] = (_Float16)a3.z; h1v[7] = (_Float16)a3.w;
      *(half8*)(stage + tile_off(r, cq * 2)) = h0v;
      *(half8*)(stage + tile_off(r, cq * 2 + 1)) = h1v;
      __syncthreads();
      uint4 v0 = *(const uint4*)(stage + tid * 32);
      uint4 v1 = *(const uint4*)(stage + tid * 32 + 16);
      *(uint4*)(outb + (size_t)kt * 8192 + tid * 32) = v0;
      *(uint4*)(outb + (size_t)kt * 8192 + tid * 32 + 16) = v1;
      __syncthreads();
    }
  } else if (bid < 2816) {
    // ---- hinit ----
    int g = (bid - 1792) * 256 + tid;
    int tile_id = g >> 9, rc = g & 511;
    int bt = tile_id >> 4, kt = tile_id & 15;
    int r = rc >> 3, c8 = rc & 7;
    const float* src = h0 + (size_t)(bt * 64 + r) * NU + kt * 64 + c8 * 8;
    float4 v0 = *(const float4*)src;
    float4 v1 = *(const float4*)(src + 4);
    half8 h;
    h[0] = (_Float16)v0.x; h[1] = (_Float16)v0.y;
    h[2] = (_Float16)v0.z; h[3] = (_Float16)v0.w;
    h[4] = (_Float16)v1.x; h[5] = (_Float16)v1.y;
    h[6] = (_Float16)v1.z; h[7] = (_Float16)v1.w;
    *(half8*)((char*)hb + (size_t)tile_id * 8192 + tile_off(r, c8)) = h;
  } else {
    // ---- zero ALL sync flags (TS*32 = 1280 ints = 320 int4; grid-stride!) --
    for (int i = tid; i < TS * 32 / 4; i += 256)
      ((int4*)done)[i] = make_int4(0, 0, 0, 0);
  }
}

// ---------------- xproj4 (verified R16; pre in serial 512-thr layout) -------
__global__ __launch_bounds__(256) void xproj4(
    const _Float16* __restrict__ X, const _Float16* __restrict__ W,
    const float* __restrict__ bias, _Float16* __restrict__ pre)
{
  __shared__ char lds[65536];  // 2 bufs x (A 16KB | B 16KB)
  const int tid = threadIdx.x;
  const int bt2 = blockIdx.x;   // 0..15
  const int ut2 = blockIdx.y;   // 0..7
  const int t   = blockIdx.z;
  const int lane = tid & 63, w = tid >> 6;
  const int wm2 = w >> 1, wn2 = w & 1;
  const int l15 = lane & 15, lk = lane >> 4;

  const char* Xb = (const char*)X + (((size_t)t * 32 + bt2 * 2) * 16) * 8192;
  const char* Wb = (const char*)W + (((size_t)t * 16 + ut2 * 2) * 32 + 16) * 8192;

  float bv[4];
#pragma unroll
  for (int nf = 0; nf < 4; ++nf)
    bv[nf] = bias[ut2 * 128 + wn2 * 64 + nf * 16 + l15];

  auto issue = [&](int p) {
    const char* src = (w < 2)
        ? Xb + (size_t)w * (16 * 8192) + (size_t)p * 8192
        : Wb + (size_t)(w - 2) * (32 * 8192) + (size_t)p * 8192;
    src += lane * 16;
    char* dst = lds + (p & 1) * 32768 + w * 8192;
#pragma unroll
    for (int i = 0; i < 8; ++i) gload16(src + i * 1024, dst + i * 1024);
  };

  floatx4 acc[4][4] = {};

  auto comp = [&](int p) {
    const char* pA = lds + (p & 1) * 32768 + wm2 * 8192;
    const char* pB = lds + (p & 1) * 32768 + 16384 + wn2 * 8192;
    __builtin_amdgcn_s_setprio(1);
#pragma unroll
    for (int kk = 0; kk < 2; ++kk) {
      half8 af[4], bf[4];
#pragma unroll
      for (int mf = 0; mf < 4; ++mf)
        af[mf] = *(const half8*)(pA + ((mf * 2 + kk) << 10) + lane * 16);
#pragma unroll
      for (int nf = 0; nf < 4; ++nf)
        bf[nf] = *(const half8*)(pB + ((nf * 2 + kk) << 10) + lane * 16);
#pragma unroll
      for (int mf = 0; mf < 4; ++mf)
#pragma unroll
        for (int nf = 0; nf < 4; ++nf)
          acc[mf][nf] = __builtin_amdgcn_mfma_f32_16x16x32_f16(
              af[mf], bf[nf], acc[mf][nf], 0, 0, 0);
    }
    __builtin_amdgcn_s_setprio(0);
  };

  issue(0);
#pragma unroll 1
  for (int p = 0; p < 16; ++p) {
    if (p + 1 < 16) {
      issue(p + 1);
      asm volatile("s_waitcnt vmcnt(8)" ::: "memory");
    } else {
      asm volatile("s_waitcnt vmcnt(0)" ::: "memory");
    }
    __builtin_amdgcn_s_barrier();
    comp(p);
    __builtin_amdgcn_s_barrier();
  }

  // epilogue: fragment-order pre stores for the 512-thr serial layout.
  char* pbase = (char*)pre + (size_t)t * (512 * 8192);
  const int bidS = (bt2 * 2 + wm2) + 32 * (ut2 * 2 + wn2);
#pragma unroll
  for (int k = 0; k < 2; ++k)
#pragma unroll
    for (int nfp = 0; nfp < 4; ++nfp) {
      _Float16 hv[8];
#pragma unroll
      for (int j = 0; j < 4; ++j) {
        hv[j]     = (_Float16)(acc[2 * k][nfp][j] + bv[nfp]);
        hv[4 + j] = (_Float16)(acc[2 * k + 1][nfp][j] + bv[nfp]);
      }
      int wS = k * 4 + nfp;
      char* dst = pbase + ((size_t)bidS * 512 + wS * 64 + lane) * 16;
      *(uint4*)dst = ((const uint4*)hv)[0];
    }
}

// ---------------- serial7: persistent chain with per-bt flag sync -----------
// One launch (cooperative, for co-residency ONLY -- grid.sync never called).
// Block (bt,ut) loops t; waits only for its 16-block bt-group via done[t][bt].
// Spin bound 2^20: a sync failure becomes a fast wrong answer, not a hang.
__global__ __launch_bounds__(512) void serial7(
    const _Float16* __restrict__ W, const _Float16* __restrict__ pre,
    _Float16* __restrict__ hb, float* __restrict__ out,
    int* __restrict__ done)
{
  __shared__ uint4 lds4[4096];          // 64 KB: 4 bufs x (A 8KB | B 8KB)
  const size_t SLOT = (size_t)NB * NU;
  const int tid = threadIdx.x, bid = blockIdx.x;
  const int bt = bid & 31, ut = bid >> 5;
  const int bidS = bt + 32 * ut;
  const int lane = tid & 63, w = tid >> 6;   // w 0..7
  const int wm = w >> 2, wn = w & 3;
  const int l15 = lane & 15, lk = lane >> 4;
  const int b0 = bt * 64, u0 = ut * 64;

#pragma unroll 1
  for (int t = 0; t < TS; ++t) {
    const char* Hb = (const char*)(hb + (size_t)(t & 1) * SLOT) +
                     (size_t)bt * 16 * 8192;
    _Float16* hnext = hb + (size_t)((t + 1) & 1) * SLOT;
    const char* Wb = (const char*)(W + (size_t)t * UD) + (size_t)ut * 32 * 8192;
    const _Float16* pret = pre + (size_t)t * SLOT;
    float* outt = out + (size_t)t * NU;

    uint4 prv = *(const uint4*)((const char*)pret +
                                ((size_t)bidS * 512 + tid) * 16);

    auto issueB = [&](int kt) {
      if (w >= 4) {
        char* la = (char*)lds4 + (kt & 3) * 16384 + w * 2048;
        const char* g = Wb + (size_t)kt * 8192 + (w - 4) * 2048 + lane * 16;
        gload16(g, la);
        gload16(g + 1024, la + 1024);
      }
    };
    auto issueA = [&](int kt) {
      if (w < 4) {
        char* la = (char*)lds4 + (kt & 3) * 16384 + w * 2048;
        const char* g = Hb + (size_t)kt * 8192 + w * 2048 + lane * 16;
        gload16(g, la);
        gload16(g + 1024, la + 1024);
      }
    };

    // W prefetch first -- flies during the flag poll
    issueB(0); issueB(1); issueB(2);

    if (t > 0) {
      if (w == 0) {
        const int* flag = &done[(t - 1) * 32 + bt];
        int spins = 0;
        while (__hip_atomic_load(flag, __ATOMIC_RELAXED,
                                 __HIP_MEMORY_SCOPE_AGENT) < 16 &&
               spins < (1 << 20)) ++spins;
        // acquire: L2-inv so h tiles read fresh cross-XCD
        (void)__hip_atomic_load(flag, __ATOMIC_ACQUIRE,
                                __HIP_MEMORY_SCOPE_AGENT);
      }
      asm volatile("s_barrier" ::: "memory");  // raw: keep B loads in flight
    }
    issueA(0); issueA(1); issueA(2);

    floatx4 acc[2] = {};

#pragma unroll 1
    for (int p = 0; p < 16; ++p) {
      if (p < 14)       asm volatile("s_waitcnt vmcnt(4)" ::: "memory");
      else if (p == 14) asm volatile("s_waitcnt vmcnt(2)" ::: "memory");
      else              asm volatile("s_waitcnt vmcnt(0)" ::: "memory");
      __builtin_amdgcn_s_barrier();
      if (p + 3 < 16) { issueA(p + 3); issueB(p + 3); }
      const char* pA = (const char*)lds4 + (p & 3) * 16384;
      const char* pB = pA + 8192;
      __builtin_amdgcn_s_setprio(1);
#pragma unroll
      for (int kk = 0; kk < 2; ++kk) {
        half8 af[2], bf;
#pragma unroll
        for (int mf = 0; mf < 2; ++mf)
          af[mf] = *(const half8*)(pA + ((((wm * 2 + mf) * 2 + kk) << 10) + lane * 16));
        bf = *(const half8*)(pB + (((wn * 2 + kk) << 10) + lane * 16));
#pragma unroll
        for (int mf = 0; mf < 2; ++mf)
          acc[mf] = __builtin_amdgcn_mfma_f32_16x16x32_f16(af[mf], bf, acc[mf], 0, 0, 0);
      }
      __builtin_amdgcn_s_setprio(0);
    }

    _Float16 prh[8];
    *(uint4*)&prh[0] = prv;
    {
      int u = u0 + wn * 16 + l15;
#pragma unroll
      for (int mf = 0; mf < 2; ++mf) {
        int brow = b0 + wm * 32 + mf * 16 + (lk << 2);
#pragma unroll
        for (int j = 0; j < 4; ++j) {
          int b = brow + j;
          float p = (float)prh[mf * 4 + j];
          float v = tanh_fast(acc[mf][j] + p);
          outt[(size_t)b * (TS * NU) + u] = v;
          *(_Float16*)((char*)hnext + (((size_t)(bt * 16 + ut)) << 13) +
                       tile_off(b & 63, (u & 63) >> 3) + (u & 7) * 2) = (_Float16)v;
        }
      }
    }
    __syncthreads();   // all threads' h/out stores complete (vmcnt drained)
    if (tid == 0)
      __hip_atomic_fetch_add(&done[t * 32 + bt], 1, __ATOMIC_RELEASE,
                             __HIP_MEMORY_SCOPE_AGENT);  // L2 writeback
  }
}

// ---------------- serial6 single-step (verified R16; launch fallback) -------
__global__ __launch_bounds__(512) void serial6(
    const _Float16* __restrict__ Wh, const _Float16* __restrict__ pret,
    const _Float16* __restrict__ hprev, _Float16* __restrict__ hnext,
    float* __restrict__ outt)
{
  __shared__ uint4 lds4[4096];
  const int tid = threadIdx.x, bid = blockIdx.x;
  const int bt = bid & 31, ut = bid >> 5;
  const int bidS = bt + 32 * ut;
  const int lane = tid & 63, w = tid >> 6;
  const int wm = w >> 2, wn = w & 3;
  const int l15 = lane & 15, lk = lane >> 4;
  const int b0 = bt * 64, u0 = ut * 64;

  uint4 prv = *(const uint4*)((const char*)pret +
                              ((size_t)bidS * 512 + tid) * 16);

  const char* Hb = (const char*)hprev + (size_t)bt * 16 * 8192;
  const char* Wb = (const char*)Wh + (size_t)ut * 32 * 8192;

  auto issue = [&](int kt) {
    char* la = (char*)lds4 + (kt & 3) * 16384 + w * 2048;
    const char* g = (w < 4)
        ? Hb + (size_t)kt * 8192 + w * 2048 + lane * 16
        : Wb + (size_t)kt * 8192 + (w - 4) * 2048 + lane * 16;
    gload16(g, la);
    gload16(g + 1024, la + 1024);
  };

  floatx4 acc[2] = {};

  issue(0);
  issue(1);
  issue(2);
#pragma unroll 1
  for (int p = 0; p < 16; ++p) {
    if (p < 14)       asm volatile("s_waitcnt vmcnt(4)" ::: "memory");
    else if (p == 14) asm volatile("s_waitcnt vmcnt(2)" ::: "memory");
    else              asm volatile("s_waitcnt vmcnt(0)" ::: "memory");
    __builtin_amdgcn_s_barrier();
    if (p + 3 < 16) issue(p + 3);
    const char* pA = (const char*)lds4 + (p & 3) * 16384;
    const char* pB = pA + 8192;
    __builtin_amdgcn_s_setprio(1);
#pragma unroll
    for (int kk = 0; kk < 2; ++kk) {
      half8 af[2], bf;
#pragma unroll
      for (int mf = 0; mf < 2; ++mf)
        af[mf] = *(const half8*)(pA + ((((wm * 2 + mf) * 2 + kk) << 10) + lane * 16));
      bf = *(const half8*)(pB + (((wn * 2 + kk) << 10) + lane * 16));
#pragma unroll
      for (int mf = 0; mf < 2; ++mf)
        acc[mf] = __builtin_amdgcn_mfma_f32_16x16x32_f16(af[mf], bf, acc[mf], 0, 0, 0);
    }
    __builtin_amdgcn_s_setprio(0);
  }

  _Float16 prh[8];
  *(uint4*)&prh[0] = prv;
  {
    int u = u0 + wn * 16 + l15;
#pragma unroll
    for (int mf = 0; mf < 2; ++mf) {
      int brow = b0 + wm * 32 + mf * 16 + (lk << 2);
#pragma unroll
      for (int j = 0; j < 4; ++j) {
        int b = brow + j;
        float p = (float)prh[mf * 4 + j];
        float v = tanh_fast(acc[mf][j] + p);
        outt[(size_t)b * (TS * NU) + u] = v;
        *(_Float16*)((char*)hnext + (((size_t)(bt * 16 + ut)) << 13) +
                     tile_off(b & 63, (u & 63) >> 3) + (u & 7) * 2) = (_Float16)v;
      }
    }
  }
}

// ================= round-1 fallback path (small ws) =========================
__global__ __launch_bounds__(256) void wprep_lin(
    const float* __restrict__ Qw, const float* __restrict__ Bt,
    _Float16* __restrict__ W, int t0, int nt)
{
  __shared__ float ldsQ[32 * 257];
  __shared__ float ldsB[TS * 8];
  const int tid = threadIdx.x;
  const int k0 = blockIdx.x * 32;
  const int u0 = blockIdx.y * 32;
  for (int i = tid; i < TS * 8; i += 256) ldsB[i] = Bt[i];
  const float* qbase = Qw + (size_t)k0 * 8192 + (size_t)u0 * 8;
#pragma unroll
  for (int i = 0; i < 8; ++i) {
    int s = i * 256 + tid;
    int r = s >> 6, c4 = s & 63;
    float4 v = *(const float4*)(qbase + (size_t)r * 8192 + c4 * 4);
    float* d = &ldsQ[r * 257 + c4 * 4];
    d[0] = v.x; d[1] = v.y; d[2] = v.z; d[3] = v.w;
  }
  __syncthreads();
  const int kl = tid & 31;
  const int ug = tid >> 5;
#pragma unroll
  for (int p = 0; p < 4; ++p) {
    int uu = p * 8 + ug;
    float q[8];
#pragma unroll
    for (int j = 0; j < 8; ++j) q[j] = ldsQ[kl * 257 + uu * 8 + j];
    size_t obase = (size_t)(u0 + uu) * 2048 + k0 + kl;
    for (int tt = 0; tt < nt; ++tt) {
      const float* bt = &ldsB[(t0 + tt) * 8];
      float v = 0.f;
#pragma unroll
      for (int j = 0; j < 8; ++j) v += q[j] * bt[j];
      W[(size_t)tt * UD + obase] = (_Float16)v;
    }
  }
}

__global__ __launch_bounds__(256) void step_gemm(
    const float* __restrict__ xt, const float* __restrict__ hp, long hstride,
    const _Float16* __restrict__ Wt, const float* __restrict__ bias,
    float* __restrict__ outt)
{
  __shared__ _Float16 ldsA[2][64 * 64];
  __shared__ _Float16 ldsB[2][128 * 64];
  const int tid = threadIdx.x;
  const int b0 = blockIdx.x * 64;
  const int u0 = blockIdx.y * 128;
  const int lane = tid & 63;
  const int wv = tid >> 6;
  const int wm = wv >> 1, wn = wv & 1;
  const int l15 = lane & 15, lk = lane >> 4;

  float4 areg[4];
  uint4 breg[4];

  auto stage_load = [&](int kt) {
    const int k0 = kt * 64;
    const float* src; size_t stride; int koff;
    if (k0 < NU) { src = hp; stride = (size_t)hstride; koff = k0; }
    else { src = xt; stride = (size_t)TS * NI; koff = k0 - NU; }
#pragma unroll
    for (int i = 0; i < 4; ++i) {
      int s = i * 256 + tid;
      int r = s >> 4, c4 = s & 15;
      areg[i] = *(const float4*)(src + (size_t)(b0 + r) * stride + koff + c4 * 4);
    }
    const _Float16* wsrc = Wt + (size_t)u0 * 2048 + k0;
#pragma unroll
    for (int i = 0; i < 4; ++i) {
      int s = i * 256 + tid;
      int u = s >> 3, c8 = s & 7;
      breg[i] = *(const uint4*)(wsrc + (size_t)u * 2048 + c8 * 8);
    }
  };

  auto stage_write = [&](int buf) {
    char* pA = (char*)&ldsA[buf][0];
    char* pB = (char*)&ldsB[buf][0];
#pragma unroll
    for (int i = 0; i < 4; ++i) {
      int s = i * 256 + tid;
      int r = s >> 4, c4 = s & 15;
      half4v h;
      h[0] = (_Float16)areg[i].x; h[1] = (_Float16)areg[i].y;
      h[2] = (_Float16)areg[i].z; h[3] = (_Float16)areg[i].w;
      int off = (r * 128 + c4 * 8) ^ ((r & 7) << 4);
      *(half4v*)(pA + off) = h;
    }
#pragma unroll
    for (int i = 0; i < 4; ++i) {
      int s = i * 256 + tid;
      int u = s >> 3, c8 = s & 7;
      int off = (u * 128 + c8 * 16) ^ ((u & 7) << 4);
      *(uint4*)(pB + off) = breg[i];
    }
  };

  floatx4 acc[2][4] = {};

  auto compute = [&](int buf) {
    const char* pA = (const char*)&ldsA[buf][0];
    const char* pB = (const char*)&ldsB[buf][0];
#pragma unroll
    for (int kk = 0; kk < 2; ++kk) {
      half8 af[2], bf[4];
#pragma unroll
      for (int mf = 0; mf < 2; ++mf) {
        int r = wm * 32 + mf * 16 + l15;
        int off = r * 128 + ((((kk << 2) | lk) ^ (r & 7)) << 4);
        af[mf] = *(const half8*)(pA + off);
      }
#pragma unroll
      for (int nf = 0; nf < 4; ++nf) {
        int u = wn * 64 + nf * 16 + l15;
        int off = u * 128 + ((((kk << 2) | lk) ^ (u & 7)) << 4);
        bf[nf] = *(const half8*)(pB + off);
      }
#pragma unroll
      for (int mf = 0; mf < 2; ++mf)
#pragma unroll
        for (int nf = 0; nf < 4; ++nf)
          acc[mf][nf] =
              __builtin_amdgcn_mfma_f32_16x16x32_f16(af[mf], bf[nf], acc[mf][nf], 0, 0, 0);
    }
  };

  stage_load(0);
  stage_write(0);
  __syncthreads();
#pragma unroll 1
  for (int kt = 0; kt < 32; ++kt) {
    int cur = kt & 1;
    if (kt + 1 < 32) stage_load(kt + 1);
    compute(cur);
    if (kt + 1 < 32) stage_write(cur ^ 1);
    __syncthreads();
  }

#pragma unroll
  for (int mf = 0; mf < 2; ++mf)
#pragma unroll
    for (int nf = 0; nf < 4; ++nf) {
      int u = u0 + wn * 64 + nf * 16 + l15;
      float bv = bias[u];
      int brow = b0 + wm * 32 + mf * 16 + (lk << 2);
#pragma unroll
      for (int j = 0; j < 4; ++j) {
        float prev = acc[mf][nf][j] + bv;
        outt[(size_t)(brow + j) * (TS * NU) + u] = tanh_fast(prev);
      }
    }
}

extern "C" void kernel_launch(void* const* d_in, const int* in_sizes, int n_in,
                              void* d_out, int out_size, void* d_ws, size_t ws_size,
                              hipStream_t stream) {
  const float* x    = (const float*)d_in[0];
  const float* h0   = (const float*)d_in[1];
  const float* Qw   = (const float*)d_in[2];
  const float* bias = (const float*)d_in[3];
  const float* Bt   = (const float*)d_in[4];
  float* out = (float*)d_out;

  char* ws = (char*)d_ws;
  const size_t w_bytes    = (size_t)UD * TS * sizeof(_Float16);      // 167.8 MB
  const size_t x_bytes    = w_bytes;                                 // 167.8 MB
  const size_t pre_bytes  = w_bytes;                                 // 167.8 MB
  const size_t slot_bytes = (size_t)NB * NU * sizeof(_Float16);      // 4 MB
  const size_t flag_bytes = (size_t)TS * 32 * sizeof(int);           // 5 KB
  const size_t need = w_bytes + x_bytes + pre_bytes + 2 * slot_bytes + flag_bytes;

  if (ws_size >= need) {
    _Float16* W   = (_Float16*)ws;
    _Float16* X   = (_Float16*)(ws + w_bytes);
    _Float16* pre = (_Float16*)(ws + w_bytes + x_bytes);
    _Float16* hb  = (_Float16*)(ws + w_bytes + x_bytes + pre_bytes);
    int* done = (int*)(ws + w_bytes + x_bytes + pre_bytes + 2 * slot_bytes);
    const size_t SLOT = (size_t)NB * NU;  // elems (4 MB)

    prep_all<<<dim3(2817), 256, 0, stream>>>(Qw, Bt, W, x, X, h0, hb, done);
    xproj4<<<dim3(16, 8, TS), 256, 0, stream>>>(X, W, bias, pre);

    const _Float16* Wa = W;
    const _Float16* prea = pre;
    _Float16* hba = hb;
    float* outa = out;
    int* donea = done;
    void* args[5] = {(void*)&Wa, (void*)&prea, (void*)&hba, (void*)&outa,
                     (void*)&donea};
    hipError_t e = hipLaunchCooperativeKernel(
        (const void*)serial7, dim3(512), dim3(512), args, 0, stream);
    if (e != hipSuccess) {
      for (int t = 0; t < TS; ++t) {
        const _Float16* hprev = hb + (size_t)(t & 1) * SLOT;
        _Float16* hnext = hb + (size_t)((t + 1) & 1) * SLOT;
        serial6<<<dim3(512), 512, 0, stream>>>(
            W + (size_t)t * UD, pre + (size_t)t * SLOT, hprev, hnext,
            out + (size_t)t * NU);
      }
    }
  } else {
    // round-1 fallback (linear W layout)
    _Float16* W = (_Float16*)ws;
    const bool big = ws_size >= w_bytes;
    if (big) wprep_lin<<<dim3(64, 32), 256, 0, stream>>>(Qw, Bt, W, 0, TS);
    for (int t = 0; t < TS; ++t) {
      const _Float16* Wtp;
      if (big) {
        Wtp = W + (size_t)t * UD;
      } else {
        wprep_lin<<<dim3(64, 32), 256, 0, stream>>>(Qw, Bt, W, t, 1);
        Wtp = W;
      }
      const float* hp = (t == 0) ? h0 : out + (size_t)(t - 1) * NU;
      long hstride = (t == 0) ? NU : (long)TS * NU;
      step_gemm<<<dim3(32, 8), 256, 0, stream>>>(
          x + (size_t)t * NI, hp, hstride, Wtp, bias, out + (size_t)t * NU);
    }
  }
}

// Round 19
// 921.769 us; speedup vs baseline: 2.3037x; 2.3037x over previous
//
#include <hip/hip_runtime.h>
#include <hip/hip_fp16.h>

#define TS 40
#define NB 2048
#define NU 1024
#define NI 1024
#define ND 2048
#define UD (1024 * 2048)  // elems in one W_t (4 MB as f16)

typedef _Float16 half8 __attribute__((ext_vector_type(8)));
typedef _Float16 half4v __attribute__((ext_vector_type(4)));
typedef float floatx4 __attribute__((ext_vector_type(4)));

__device__ __forceinline__ float tanh_fast(float v) {
  float e = __expf(2.0f * v);
  return 1.0f - 2.0f / (e + 1.0f);  // inf-safe
}

__device__ __forceinline__ void gload16(const void* g, void* l) {
  __builtin_amdgcn_global_load_lds(
      (const __attribute__((address_space(1))) void*)g,
      (__attribute__((address_space(3))) void*)l, 16, 0, 0);
}

// ===== fragment-major tile layout (verified R6-R16) =========================
// tile = 64x64 f16 = 8192 B as 512 x 16B chunks.
// chunk(r,c8) = ((r>>4)*2 + (c8>>2))*64 + (c8&3)*16 + (r&15)
__device__ __forceinline__ int tile_off(int r, int c8) {
  return (((((r >> 4) * 2 + (c8 >> 2)) << 6) + ((c8 & 3) << 4) + (r & 15)) << 4);
}

// W_tiled:  [t][ut 0..15][kt 0..31][8192B]  (kt<16: h-part, kt>=16: x-part)
// X_tiled:  [t][bt 0..31][kt 0..15][8192B]
// h_tiled:  [slot][bt 0..31][ut 0..15][8192B]
// pre_frag: [t][bid_s = bt+32*ut][tid_s 0..511][8 f16]  (4 MB per t)

// ---------------- merged prep (verified R14/R16) ----------------------------
__global__ __launch_bounds__(256) void prep_all(
    const float* __restrict__ Qw, const float* __restrict__ Bt,
    _Float16* __restrict__ W,
    const float* __restrict__ x, _Float16* __restrict__ X,
    const float* __restrict__ h0, _Float16* __restrict__ hb)
{
  __shared__ char shm[66816];  // wprep: 64KB Q + 1280B B (TS*8 floats)
  const int tid = threadIdx.x;
  const int bid = blockIdx.x;

  if (bid < 512) {
    // ---- wprep ----
    _Float16* ldsQ = (_Float16*)shm;
    float* ldsB = (float*)(shm + 65536);
    const int kt = bid & 31;
    const int ut = bid >> 5;
    for (int i = tid; i < TS * 8; i += 256) ldsB[i] = Bt[i];
    const float* qb = Qw + (size_t)(kt * 64) * 8192 + ut * 512;
#pragma unroll
    for (int i = 0; i < 32; ++i) {
      int s = i * 256 + tid;
      int dk = s >> 7, c4 = s & 127;
      float4 v = *(const float4*)(qb + (size_t)dk * 8192 + c4 * 4);
      _Float16* d = &ldsQ[dk * 512 + c4 * 4];
      d[0] = (_Float16)v.x; d[1] = (_Float16)v.y;
      d[2] = (_Float16)v.z; d[3] = (_Float16)v.w;
    }
    __syncthreads();
    const int w = tid >> 6, lane = tid & 63;
    const int dur = lane & 7, ko = lane >> 3;
#pragma unroll 1
    for (int sp = 0; sp < 2; ++sp) {
      const int stripe = w * 2 + sp;
      const int du = stripe * 8 + dur;
      float Q[8][8];
#pragma unroll
      for (int j = 0; j < 8; ++j)
#pragma unroll
        for (int q = 0; q < 8; ++q)
          Q[j][q] = (float)ldsQ[(ko * 8 + j) * 512 + du * 8 + q];
      const int obase = tile_off(du, ko);
#pragma unroll 1
      for (int t = 0; t < TS; ++t) {
        float b[8];
#pragma unroll
        for (int q = 0; q < 8; ++q) b[q] = ldsB[t * 8 + q];
        half8 v;
#pragma unroll
        for (int j = 0; j < 8; ++j) {
          float s = 0.f;
#pragma unroll
          for (int q = 0; q < 8; ++q) s += Q[j][q] * b[q];
          v[j] = (_Float16)s;
        }
        size_t tile = ((size_t)t * 16 + ut) * 32 + kt;
        *(half8*)((char*)W + tile * 8192 + obase) = v;
      }
    }
  } else if (bid < 1792) {
    // ---- xprep ----
    char* stage = shm;
    const int b2 = bid - 512;
    const int bt = b2 & 31, t = b2 >> 5;
    char* outb = (char*)X + ((size_t)(t * 32 + bt) * 16) * 8192;
    const int r = tid >> 2, cq = tid & 3;
#pragma unroll 1
    for (int kt = 0; kt < 16; ++kt) {
      const float* src =
          x + (size_t)(bt * 64 + r) * (TS * NI) + (size_t)t * NI + kt * 64 + cq * 16;
      float4 a0 = *(const float4*)(src);
      float4 a1 = *(const float4*)(src + 4);
      float4 a2 = *(const float4*)(src + 8);
      float4 a3 = *(const float4*)(src + 12);
      half8 h0v, h1v;
      h0v[0] = (_Float16)a0.x; h0v[1] = (_Float16)a0.y;
      h0v[2] = (_Float16)a0.z; h0v[3] = (_Float16)a0.w;
      h0v[4] = (_Float16)a1.x; h0v[5] = (_Float16)a1.y;
      h0v[6] = (_Float16)a1.z; h0v[7] = (_Float16)a1.w;
      h1v[0] = (_Float16)a2.x; h1v[1] = (_Float16)a2.y;
      h1v[2] = (_Float16)a2.z; h1v[3] = (_Float16)a2.w;
      h1v[4] = (_Float16)a3.x; h1v[5] = (_Float16)a3.y;
      h1v[6] = (_Float16)a3.z; h1v[7] = (_Float16)a3.w;
      *(half8*)(stage + tile_off(r, cq * 2)) = h0v;
      *(half8*)(stage + tile_off(r, cq * 2 + 1)) = h1v;
      __syncthreads();
      uint4 v0 = *(const uint4*)(stage + tid * 32);
      uint4 v1 = *(const uint4*)(stage + tid * 32 + 16);
      *(uint4*)(outb + (size_t)kt * 8192 + tid * 32) = v0;
      *(uint4*)(outb + (size_t)kt * 8192 + tid * 32 + 16) = v1;
      __syncthreads();
    }
  } else {
    // ---- hinit ----
    int g = (bid - 1792) * 256 + tid;
    int tile_id = g >> 9, rc = g & 511;
    int bt = tile_id >> 4, kt = tile_id & 15;
    int r = rc >> 3, c8 = rc & 7;
    const float* src = h0 + (size_t)(bt * 64 + r) * NU + kt * 64 + c8 * 8;
    float4 v0 = *(const float4*)src;
    float4 v1 = *(const float4*)(src + 4);
    half8 h;
    h[0] = (_Float16)v0.x; h[1] = (_Float16)v0.y;
    h[2] = (_Float16)v0.z; h[3] = (_Float16)v0.w;
    h[4] = (_Float16)v1.x; h[5] = (_Float16)v1.y;
    h[6] = (_Float16)v1.z; h[7] = (_Float16)v1.w;
    *(half8*)((char*)hb + (size_t)tile_id * 8192 + tile_off(r, c8)) = h;
  }
}

// ---------------- xproj4: pre_frag[t] = x_t @ Wx_t + bias -------------------
// Verified R12/R16 main loop; epilogue in serial6's 512-thr fragment layout.
__global__ __launch_bounds__(256) void xproj4(
    const _Float16* __restrict__ X, const _Float16* __restrict__ W,
    const float* __restrict__ bias, _Float16* __restrict__ pre)
{
  __shared__ char lds[65536];  // 2 bufs x (A 16KB | B 16KB)
  const int tid = threadIdx.x;
  const int bt2 = blockIdx.x;   // 0..15
  const int ut2 = blockIdx.y;   // 0..7
  const int t   = blockIdx.z;
  const int lane = tid & 63, w = tid >> 6;
  const int wm2 = w >> 1, wn2 = w & 1;
  const int l15 = lane & 15, lk = lane >> 4;

  const char* Xb = (const char*)X + (((size_t)t * 32 + bt2 * 2) * 16) * 8192;
  const char* Wb = (const char*)W + (((size_t)t * 16 + ut2 * 2) * 32 + 16) * 8192;

  float bv[4];
#pragma unroll
  for (int nf = 0; nf < 4; ++nf)
    bv[nf] = bias[ut2 * 128 + wn2 * 64 + nf * 16 + l15];

  auto issue = [&](int p) {
    const char* src = (w < 2)
        ? Xb + (size_t)w * (16 * 8192) + (size_t)p * 8192
        : Wb + (size_t)(w - 2) * (32 * 8192) + (size_t)p * 8192;
    src += lane * 16;
    char* dst = lds + (p & 1) * 32768 + w * 8192;
#pragma unroll
    for (int i = 0; i < 8; ++i) gload16(src + i * 1024, dst + i * 1024);
  };

  floatx4 acc[4][4] = {};

  auto comp = [&](int p) {
    const char* pA = lds + (p & 1) * 32768 + wm2 * 8192;
    const char* pB = lds + (p & 1) * 32768 + 16384 + wn2 * 8192;
    __builtin_amdgcn_s_setprio(1);
#pragma unroll
    for (int kk = 0; kk < 2; ++kk) {
      half8 af[4], bf[4];
#pragma unroll
      for (int mf = 0; mf < 4; ++mf)
        af[mf] = *(const half8*)(pA + ((mf * 2 + kk) << 10) + lane * 16);
#pragma unroll
      for (int nf = 0; nf < 4; ++nf)
        bf[nf] = *(const half8*)(pB + ((nf * 2 + kk) << 10) + lane * 16);
#pragma unroll
      for (int mf = 0; mf < 4; ++mf)
#pragma unroll
        for (int nf = 0; nf < 4; ++nf)
          acc[mf][nf] = __builtin_amdgcn_mfma_f32_16x16x32_f16(
              af[mf], bf[nf], acc[mf][nf], 0, 0, 0);
    }
    __builtin_amdgcn_s_setprio(0);
  };

  issue(0);
#pragma unroll 1
  for (int p = 0; p < 16; ++p) {
    if (p + 1 < 16) {
      issue(p + 1);
      asm volatile("s_waitcnt vmcnt(8)" ::: "memory");
    } else {
      asm volatile("s_waitcnt vmcnt(0)" ::: "memory");
    }
    __builtin_amdgcn_s_barrier();
    comp(p);
    __builtin_amdgcn_s_barrier();
  }

  // epilogue: fragment-order pre stores for serial6 (512-thr) layout.
  // serial6 thread (w_s, lane) covers rows (w_s>>2)*32+mf*16+lk*4+j,
  // col (w_s&3)*16+l15; our acc[mfp][nfp] -> w_s=(mfp>>1)*4+nfp, slot=(mfp&1)*4+j.
  char* pbase = (char*)pre + (size_t)t * (512 * 8192);
  const int bidS = (bt2 * 2 + wm2) + 32 * (ut2 * 2 + wn2);
#pragma unroll
  for (int k = 0; k < 2; ++k)
#pragma unroll
    for (int nfp = 0; nfp < 4; ++nfp) {
      _Float16 hv[8];
#pragma unroll
      for (int j = 0; j < 4; ++j) {
        hv[j]     = (_Float16)(acc[2 * k][nfp][j] + bv[nfp]);
        hv[4 + j] = (_Float16)(acc[2 * k + 1][nfp][j] + bv[nfp]);
      }
      int wS = k * 4 + nfp;
      char* dst = pbase + ((size_t)bidS * 512 + wS * 64 + lane) * 16;
      *(uint4*)dst = ((const uint4*)hv)[0];
    }
}

// ---------------- serial6: h_t = tanh(h_{t-1} @ Wh_t + pre_t) ---------------
// 64x64 tile, 16 phases, ring-4 DMA depth-3, counted vmcnt, raw barriers.
// 512 threads (8 waves -> 4 waves/SIMD at 2 blocks/CU).
// Wave w owns 32x16 sub-tile: wm=w>>2, wn=w&3; acc[2][4 elem].
__global__ __launch_bounds__(512) void serial6(
    const _Float16* __restrict__ Wh,    // W + t*UD (tiled)
    const _Float16* __restrict__ pret,  // pre_frag + t*SLOT
    const _Float16* __restrict__ hprev, // tiled
    _Float16* __restrict__ hnext,       // tiled
    float* __restrict__ outt)           // out + t*NU, row stride TS*NU
{
  __shared__ uint4 lds4[4096];          // 64 KB: 4 bufs x (A 8KB | B 8KB)
  const int tid = threadIdx.x, bid = blockIdx.x;
  const int bt = bid & 31, ut = bid >> 5;
  const int bidS = bt + 32 * ut;
  const int lane = tid & 63, w = tid >> 6;   // w 0..7
  const int wm = w >> 2, wn = w & 3;
  const int l15 = lane & 15, lk = lane >> 4;
  const int b0 = bt * 64, u0 = ut * 64;

  // coalesced frag-order pre prefetch (oldest vmcnt entry; 1 dwordx4)
  uint4 prv;
  {
    const uint4* pp = (const uint4*)((const char*)pret +
                                     ((size_t)bidS * 512 + tid) * 16);
    prv = pp[0];
  }

  const char* Hb = (const char*)hprev + (size_t)bt * 16 * 8192;
  const char* Wb = (const char*)Wh + (size_t)ut * 32 * 8192;

  auto issue = [&](int kt) {
    // 8 waves x 2KB: w<4 stage A (8KB), w>=4 stage B (8KB)
    char* la = (char*)lds4 + (kt & 3) * 16384 + w * 2048;
    const char* g = (w < 4)
        ? Hb + (size_t)kt * 8192 + w * 2048 + lane * 16
        : Wb + (size_t)kt * 8192 + (w - 4) * 2048 + lane * 16;
    gload16(g, la);
    gload16(g + 1024, la + 1024);
  };

  floatx4 acc[2] = {};

  issue(0);
  issue(1);
  issue(2);
#pragma unroll 1
  for (int p = 0; p < 16; ++p) {
    // per wave 2 loads/phase; outstanding = 3 phases = 6 (+1 pre at p=0)
    if (p < 14)       asm volatile("s_waitcnt vmcnt(4)" ::: "memory");
    else if (p == 14) asm volatile("s_waitcnt vmcnt(2)" ::: "memory");
    else              asm volatile("s_waitcnt vmcnt(0)" ::: "memory");
    __builtin_amdgcn_s_barrier();      // all waves' phase-p data in LDS
    if (p + 3 < 16) issue(p + 3);      // buf (p-1)&3 free
    const char* pA = (const char*)lds4 + (p & 3) * 16384;
    const char* pB = pA + 8192;
    __builtin_amdgcn_s_setprio(1);
#pragma unroll
    for (int kk = 0; kk < 2; ++kk) {
      half8 af[2], bf;
#pragma unroll
      for (int mf = 0; mf < 2; ++mf)
        af[mf] = *(const half8*)(pA + ((((wm * 2 + mf) * 2 + kk) << 10) + lane * 16));
      bf = *(const half8*)(pB + (((wn * 2 + kk) << 10) + lane * 16));
#pragma unroll
      for (int mf = 0; mf < 2; ++mf)
        acc[mf] = __builtin_amdgcn_mfma_f32_16x16x32_f16(af[mf], bf, acc[mf], 0, 0, 0);
    }
    __builtin_amdgcn_s_setprio(0);
  }

  _Float16 prh[8];
  *(uint4*)&prh[0] = prv;
  {
    int u = u0 + wn * 16 + l15;
#pragma unroll
    for (int mf = 0; mf < 2; ++mf) {
      int brow = b0 + wm * 32 + mf * 16 + (lk << 2);
#pragma unroll
      for (int j = 0; j < 4; ++j) {
        int b = brow + j;
        float p = (float)prh[mf * 4 + j];
        float v = tanh_fast(acc[mf][j] + p);
        outt[(size_t)b * (TS * NU) + u] = v;
        *(_Float16*)((char*)hnext + (((size_t)(bt * 16 + ut)) << 13) +
                     tile_off(b & 63, (u & 63) >> 3) + (u & 7) * 2) = (_Float16)v;
      }
    }
  }
}

// ================= round-1 fallback path (small ws) =========================
__global__ __launch_bounds__(256) void wprep_lin(
    const float* __restrict__ Qw, const float* __restrict__ Bt,
    _Float16* __restrict__ W, int t0, int nt)
{
  __shared__ float ldsQ[32 * 257];
  __shared__ float ldsB[TS * 8];
  const int tid = threadIdx.x;
  const int k0 = blockIdx.x * 32;
  const int u0 = blockIdx.y * 32;
  for (int i = tid; i < TS * 8; i += 256) ldsB[i] = Bt[i];
  const float* qbase = Qw + (size_t)k0 * 8192 + (size_t)u0 * 8;
#pragma unroll
  for (int i = 0; i < 8; ++i) {
    int s = i * 256 + tid;
    int r = s >> 6, c4 = s & 63;
    float4 v = *(const float4*)(qbase + (size_t)r * 8192 + c4 * 4);
    float* d = &ldsQ[r * 257 + c4 * 4];
    d[0] = v.x; d[1] = v.y; d[2] = v.z; d[3] = v.w;
  }
  __syncthreads();
  const int kl = tid & 31;
  const int ug = tid >> 5;
#pragma unroll
  for (int p = 0; p < 4; ++p) {
    int uu = p * 8 + ug;
    float q[8];
#pragma unroll
    for (int j = 0; j < 8; ++j) q[j] = ldsQ[kl * 257 + uu * 8 + j];
    size_t obase = (size_t)(u0 + uu) * 2048 + k0 + kl;
    for (int tt = 0; tt < nt; ++tt) {
      const float* bt = &ldsB[(t0 + tt) * 8];
      float v = 0.f;
#pragma unroll
      for (int j = 0; j < 8; ++j) v += q[j] * bt[j];
      W[(size_t)tt * UD + obase] = (_Float16)v;
    }
  }
}

__global__ __launch_bounds__(256) void step_gemm(
    const float* __restrict__ xt, const float* __restrict__ hp, long hstride,
    const _Float16* __restrict__ Wt, const float* __restrict__ bias,
    float* __restrict__ outt)
{
  __shared__ _Float16 ldsA[2][64 * 64];
  __shared__ _Float16 ldsB[2][128 * 64];
  const int tid = threadIdx.x;
  const int b0 = blockIdx.x * 64;
  const int u0 = blockIdx.y * 128;
  const int lane = tid & 63;
  const int wv = tid >> 6;
  const int wm = wv >> 1, wn = wv & 1;
  const int l15 = lane & 15, lk = lane >> 4;

  float4 areg[4];
  uint4 breg[4];

  auto stage_load = [&](int kt) {
    const int k0 = kt * 64;
    const float* src; size_t stride; int koff;
    if (k0 < NU) { src = hp; stride = (size_t)hstride; koff = k0; }
    else { src = xt; stride = (size_t)TS * NI; koff = k0 - NU; }
#pragma unroll
    for (int i = 0; i < 4; ++i) {
      int s = i * 256 + tid;
      int r = s >> 4, c4 = s & 15;
      areg[i] = *(const float4*)(src + (size_t)(b0 + r) * stride + koff + c4 * 4);
    }
    const _Float16* wsrc = Wt + (size_t)u0 * 2048 + k0;
#pragma unroll
    for (int i = 0; i < 4; ++i) {
      int s = i * 256 + tid;
      int u = s >> 3, c8 = s & 7;
      breg[i] = *(const uint4*)(wsrc + (size_t)u * 2048 + c8 * 8);
    }
  };

  auto stage_write = [&](int buf) {
    char* pA = (char*)&ldsA[buf][0];
    char* pB = (char*)&ldsB[buf][0];
#pragma unroll
    for (int i = 0; i < 4; ++i) {
      int s = i * 256 + tid;
      int r = s >> 4, c4 = s & 15;
      half4v h;
      h[0] = (_Float16)areg[i].x; h[1] = (_Float16)areg[i].y;
      h[2] = (_Float16)areg[i].z; h[3] = (_Float16)areg[i].w;
      int off = (r * 128 + c4 * 8) ^ ((r & 7) << 4);
      *(half4v*)(pA + off) = h;
    }
#pragma unroll
    for (int i = 0; i < 4; ++i) {
      int s = i * 256 + tid;
      int u = s >> 3, c8 = s & 7;
      int off = (u * 128 + c8 * 16) ^ ((u & 7) << 4);
      *(uint4*)(pB + off) = breg[i];
    }
  };

  floatx4 acc[2][4] = {};

  auto compute = [&](int buf) {
    const char* pA = (const char*)&ldsA[buf][0];
    const char* pB = (const char*)&ldsB[buf][0];
#pragma unroll
    for (int kk = 0; kk < 2; ++kk) {
      half8 af[2], bf[4];
#pragma unroll
      for (int mf = 0; mf < 2; ++mf) {
        int r = wm * 32 + mf * 16 + l15;
        int off = r * 128 + ((((kk << 2) | lk) ^ (r & 7)) << 4);
        af[mf] = *(const half8*)(pA + off);
      }
#pragma unroll
      for (int nf = 0; nf < 4; ++nf) {
        int u = wn * 64 + nf * 16 + l15;
        int off = u * 128 + ((((kk << 2) | lk) ^ (u & 7)) << 4);
        bf[nf] = *(const half8*)(pB + off);
      }
#pragma unroll
      for (int mf = 0; mf < 2; ++mf)
#pragma unroll
        for (int nf = 0; nf < 4; ++nf)
          acc[mf][nf] =
              __builtin_amdgcn_mfma_f32_16x16x32_f16(af[mf], bf[nf], acc[mf][nf], 0, 0, 0);
    }
  };

  stage_load(0);
  stage_write(0);
  __syncthreads();
#pragma unroll 1
  for (int kt = 0; kt < 32; ++kt) {
    int cur = kt & 1;
    if (kt + 1 < 32) stage_load(kt + 1);
    compute(cur);
    if (kt + 1 < 32) stage_write(cur ^ 1);
    __syncthreads();
  }

#pragma unroll
  for (int mf = 0; mf < 2; ++mf)
#pragma unroll
    for (int nf = 0; nf < 4; ++nf) {
      int u = u0 + wn * 64 + nf * 16 + l15;
      float bv = bias[u];
      int brow = b0 + wm * 32 + mf * 16 + (lk << 2);
#pragma unroll
      for (int j = 0; j < 4; ++j) {
        float prev = acc[mf][nf][j] + bv;
        outt[(size_t)(brow + j) * (TS * NU) + u] = tanh_fast(prev);
      }
    }
}

extern "C" void kernel_launch(void* const* d_in, const int* in_sizes, int n_in,
                              void* d_out, int out_size, void* d_ws, size_t ws_size,
                              hipStream_t stream) {
  const float* x    = (const float*)d_in[0];
  const float* h0   = (const float*)d_in[1];
  const float* Qw   = (const float*)d_in[2];
  const float* bias = (const float*)d_in[3];
  const float* Bt   = (const float*)d_in[4];
  float* out = (float*)d_out;

  char* ws = (char*)d_ws;
  const size_t w_bytes    = (size_t)UD * TS * sizeof(_Float16);      // 167.8 MB
  const size_t x_bytes    = w_bytes;                                 // 167.8 MB
  const size_t pre_bytes  = w_bytes;                                 // 167.8 MB
  const size_t slot_bytes = (size_t)NB * NU * sizeof(_Float16);      // 4 MB
  const size_t need = w_bytes + x_bytes + pre_bytes + 2 * slot_bytes;

  if (ws_size >= need) {
    _Float16* W   = (_Float16*)ws;
    _Float16* X   = (_Float16*)(ws + w_bytes);
    _Float16* pre = (_Float16*)(ws + w_bytes + x_bytes);
    _Float16* hb  = (_Float16*)(ws + w_bytes + x_bytes + pre_bytes);
    const size_t SLOT = (size_t)NB * NU;  // elems (4 MB)

    prep_all<<<dim3(2816), 256, 0, stream>>>(Qw, Bt, W, x, X, h0, hb);
    xproj4<<<dim3(16, 8, TS), 256, 0, stream>>>(X, W, bias, pre);

    for (int t = 0; t < TS; ++t) {
      const _Float16* hprev = hb + (size_t)(t & 1) * SLOT;
      _Float16* hnext = hb + (size_t)((t + 1) & 1) * SLOT;
      serial6<<<dim3(512), 512, 0, stream>>>(
          W + (size_t)t * UD, pre + (size_t)t * SLOT, hprev, hnext,
          out + (size_t)t * NU);
    }
  } else {
    // round-1 fallback (linear W layout)
    _Float16* W = (_Float16*)ws;
    const bool big = ws_size >= w_bytes;
    if (big) wprep_lin<<<dim3(64, 32), 256, 0, stream>>>(Qw, Bt, W, 0, TS);
    for (int t = 0; t < TS; ++t) {
      const _Float16* Wtp;
      if (big) {
        Wtp = W + (size_t)t * UD;
      } else {
        wprep_lin<<<dim3(64, 32), 256, 0, stream>>>(Qw, Bt, W, t, 1);
        Wtp = W;
      }
      const float* hp = (t == 0) ? h0 : out + (size_t)(t - 1) * NU;
      long hstride = (t == 0) ? NU : (long)TS * NU;
      step_gemm<<<dim3(32, 8), 256, 0, stream>>>(
          x + (size_t)t * NI, hp, hstride, Wtp, bias, out + (size_t)t * NU);
    }
  }
}